// Round 6
// baseline (149.293 us; speedup 1.0000x reference)
//
#include <hip/hip_runtime.h>
#include <hip/hip_bf16.h>

// Problem-fixed shapes (XLMRForTokenClassification: B=128, S=512, H=1024, L=9)
#define B_ 128
#define S_ 512
#define H_ 1024
#define L_ 9

#define NBLK 256        // 2 blocks per batch
#define NTHR 512        // 8 waves per block
#define WPB  8
#define REPS 8          // diagnostic: replicate compute kernel 8x

// DPP-based wave64 sum: total lands in lane 63.
#define DPP_ADD_(v, ctrl, rm, bm)                                              \
    v += __int_as_float(__builtin_amdgcn_update_dpp(                           \
        0, __float_as_int(v), ctrl, rm, bm, true))

__device__ __forceinline__ float wave_sum63(float v) {
    DPP_ADD_(v, 0x111, 0xf, 0xf);  // row_shr:1
    DPP_ADD_(v, 0x112, 0xf, 0xf);  // row_shr:2
    DPP_ADD_(v, 0x114, 0xf, 0xe);  // row_shr:4
    DPP_ADD_(v, 0x118, 0xf, 0xc);  // row_shr:8
    DPP_ADD_(v, 0x142, 0xa, 0xf);  // row_bcast:15 -> rows 1,3
    DPP_ADD_(v, 0x143, 0xc, 0xf);  // row_bcast:31 -> rows 2,3
    return v;
}

// ---------------------------------------------------------------------------
// Compute kernel (identical structure to R5). blockIdx -> (batch, half).
// Phase A: ballot scans -> item list in LDS; bias-only NLL + active count.
// Phase B: scalar meta via one LDS read + v_readlane; saddr row loads;
//   3-deep rotating pipeline; W in registers; DPP reduction.
// Writes per-block partials (same values every rep -> deterministic).
// ---------------------------------------------------------------------------
__global__ __launch_bounds__(NTHR, 2) void fused_kernel(
    const float* __restrict__ x,       // [B,S,H]
    const int*   __restrict__ labels,  // [B,S]
    const int*   __restrict__ lmask,   // [B,S]
    const int*   __restrict__ bpe,     // [B,S]
    const float* __restrict__ W,       // [L,H]
    const float* __restrict__ bias,    // [L]
    float* __restrict__ part_sum,      // [NBLK]
    float* __restrict__ part_cnt)      // [NBLK]
{
    const int tid  = threadIdx.x;
    const int lane = tid & 63;
    const int wv   = tid >> 6;
    const int b    = blockIdx.x >> 1;
    const int half = blockIdx.x & 1;

    __shared__ int      wcnt[WPB], wcnt2[WPB];
    __shared__ int      srcbuf[S_];
    __shared__ unsigned items[S_];
    __shared__ float    red[WPB], redc[WPB];

    // ---- scan-critical int loads first ----
    const int gpos = b * S_ + tid;
    const int bpev = bpe[gpos];
    const int lab  = labels[gpos];
    const int lmv  = lmask[gpos];

    // ---- stage W into registers (latency hides under phase A) ----
    const float4* W4 = reinterpret_cast<const float4*>(W);
    float4 wreg[L_][4];
#pragma unroll
    for (int l = 0; l < L_; ++l)
#pragma unroll
        for (int k = 0; k < 4; ++k)
            wreg[l][k] = W4[l * (H_ / 4) + lane + 64 * k];
    float bl[L_];
#pragma unroll
    for (int l = 0; l < L_; ++l) bl[l] = bias[l];

    // ---- phase A: per-batch scans ----
    const unsigned long long lmlt = (1ull << lane) - 1ull;

    const int vv = (bpev == 1) ? 1 : 0;
    const unsigned long long ball = __ballot(vv != 0);
    const int rank = (int)__popcll(ball & lmlt);
    if (lane == 0) wcnt[wv] = (int)__popcll(ball);
    __syncthreads();
    int prefix = 0, n_valid = 0;
#pragma unroll
    for (int w = 0; w < WPB; ++w) {
        const int c = wcnt[w];
        if (w < wv) prefix += c;
        n_valid += c;
    }
    if (vv) srcbuf[prefix + rank] = tid;
    __syncthreads();

    const bool act = (lmv == 1) && (lab != 0);
    const bool rowitem = act && (tid < n_valid);
    const unsigned long long ball2 = __ballot(rowitem);
    const int rank2 = (int)__popcll(ball2 & lmlt);
    if (lane == 0) wcnt2[wv] = (int)__popcll(ball2);
    __syncthreads();
    int prefix2 = 0, m = 0;
#pragma unroll
    for (int w = 0; w < WPB; ++w) {
        const int c = wcnt2[w];
        if (w < wv) prefix2 += c;
        m += c;
    }
    if (rowitem)
        items[prefix2 + rank2] = ((unsigned)srcbuf[tid] << 4) | (unsigned)lab;

    // bias-only NLL (zeroed rows: logits == bias) + denominator (half==0 only)
    float bnll = 0.f, bc = 0.f;
    if (half == 0) {
        if (act && tid >= n_valid) {
            float mx = bl[0];
#pragma unroll
            for (int l = 1; l < L_; ++l) mx = fmaxf(mx, bl[l]);
            float se = 0.f;
#pragma unroll
            for (int l = 0; l < L_; ++l) se += __expf(bl[l] - mx);
            bnll = mx + __logf(se) - bl[lab];
        }
        bc = act ? 1.f : 0.f;
    }
    __syncthreads();   // items[] visible

    // ---- phase B ----
    const float4* X4 = reinterpret_cast<const float4*>(x)
                     + (size_t)b * S_ * (H_ / 4);
    const int p  = half + 2 * wv;                       // first item index
    const int nt = (m > p) ? ((m - p + 15) >> 4) : 0;   // my item count

    const int midx = p + 16 * lane;
    unsigned ereg = (midx < m) ? items[midx] : 0u;

    float lsum = 0.f;

    auto rowbase = [&](int t) -> const float4* {
        const unsigned e = (unsigned)__builtin_amdgcn_readlane((int)ereg, t);
        return X4 + (size_t)(e >> 4) * (H_ / 4);   // scalar base -> saddr
    };

    float4 A0, A1, A2, A3, B0, B1, B2, B3, C0, C1, C2, C3;

#define LOADROW(R0, R1, R2, R3, t)                                             \
    {                                                                          \
        const float4* _p = rowbase(t);                                         \
        R0 = _p[lane]; R1 = _p[lane + 64];                                     \
        R2 = _p[lane + 128]; R3 = _p[lane + 192];                              \
    }

    auto compute = [&](int t, float4 v0, float4 v1, float4 v2, float4 v3) {
        float acc[L_];
#pragma unroll
        for (int l = 0; l < L_; ++l) {
            acc[l] = v0.x * wreg[l][0].x + v0.y * wreg[l][0].y
                   + v0.z * wreg[l][0].z + v0.w * wreg[l][0].w
                   + v1.x * wreg[l][1].x + v1.y * wreg[l][1].y
                   + v1.z * wreg[l][1].z + v1.w * wreg[l][1].w
                   + v2.x * wreg[l][2].x + v2.y * wreg[l][2].y
                   + v2.z * wreg[l][2].z + v2.w * wreg[l][2].w
                   + v3.x * wreg[l][3].x + v3.y * wreg[l][3].y
                   + v3.z * wreg[l][3].z + v3.w * wreg[l][3].w;
        }
#pragma unroll
        for (int l = 0; l < L_; ++l) acc[l] = wave_sum63(acc[l]);
        if (lane == 63) {
            const int lb = (int)(__builtin_amdgcn_readlane((int)ereg, t) & 0xF);
            float lg[L_];
#pragma unroll
            for (int l = 0; l < L_; ++l) lg[l] = acc[l] + bl[l];
            float mx = lg[0];
#pragma unroll
            for (int l = 1; l < L_; ++l) mx = fmaxf(mx, lg[l]);
            float se = 0.f;
#pragma unroll
            for (int l = 0; l < L_; ++l) se += __expf(lg[l] - mx);
            float sel = lg[0];
#pragma unroll
            for (int l = 1; l < L_; ++l) sel = (lb == l) ? lg[l] : sel;
            lsum += mx + __logf(se) - sel;
        }
    };

    if (nt > 0) {
        LOADROW(A0, A1, A2, A3, 0);
        if (nt > 1) LOADROW(B0, B1, B2, B3, 1);
        int t = 0;
        while (t + 2 < nt) {               // 3-deep rotating pipeline
            LOADROW(C0, C1, C2, C3, t + 2);
            compute(t, A0, A1, A2, A3);
            if (t + 3 < nt) LOADROW(A0, A1, A2, A3, t + 3);
            compute(t + 1, B0, B1, B2, B3);
            if (t + 4 < nt) LOADROW(B0, B1, B2, B3, t + 4);
            compute(t + 2, C0, C1, C2, C3);
            t += 3;
        }
        if (t < nt)     compute(t, A0, A1, A2, A3);
        if (t + 1 < nt) compute(t + 1, B0, B1, B2, B3);
    }
#undef LOADROW

    // ---- block reduce -> plain partial stores (finalize is a later dispatch
    //      on the same stream; kernel boundary orders the writes) ----
    const float bs = wave_sum63(bnll);
    const float cs = wave_sum63(bc);
    if (lane == 63) { red[wv] = lsum + bs; redc[wv] = cs; }
    __syncthreads();
    if (tid == 0) {
        float a = 0.f, c = 0.f;
#pragma unroll
        for (int w = 0; w < WPB; ++w) { a += red[w]; c += redc[w]; }
        part_sum[blockIdx.x] = a;
        part_cnt[blockIdx.x] = c;
    }
}

// ---------------------------------------------------------------------------
// Finalize: reduce partials -> scalar loss (separate tiny dispatch)
// ---------------------------------------------------------------------------
__global__ void finalize_kernel(const float* __restrict__ part_sum,
                                const float* __restrict__ part_cnt,
                                float* __restrict__ out) {
    const int lane = threadIdx.x;  // 64 threads
    float s = 0.f, c = 0.f;
    for (int i = lane; i < NBLK; i += 64) {
        s += part_sum[i];
        c += part_cnt[i];
    }
#pragma unroll
    for (int off = 32; off > 0; off >>= 1) {
        s += __shfl_xor(s, off, 64);
        c += __shfl_xor(c, off, 64);
    }
    if (lane == 0) out[0] = s / fmaxf(c, 1.0f);
}

extern "C" void kernel_launch(void* const* d_in, const int* in_sizes, int n_in,
                              void* d_out, int out_size, void* d_ws, size_t ws_size,
                              hipStream_t stream) {
    const float* x      = (const float*)d_in[0];  // [B,S,H] f32
    const int*   labels = (const int*)d_in[1];    // [B,S]
    const int*   lmask  = (const int*)d_in[2];    // [B,S]
    const int*   bpe    = (const int*)d_in[3];    // [B,S]
    const float* W      = (const float*)d_in[4];  // [L,H] f32
    const float* bias   = (const float*)d_in[5];  // [L]  f32

    // Workspace: part_sum[NBLK] | part_cnt[NBLK]
    float* part_sum = (float*)d_ws;
    float* part_cnt = part_sum + NBLK;

    // DIAGNOSTIC: run the identical compute kernel REPS times (each rep
    // recomputes and rewrites the same partials -> deterministic output).
    // dur_us ~= floor + REPS * K  ->  K = (dur_R6 - dur_R5) / (REPS - 1).
    for (int r = 0; r < REPS; ++r) {
        fused_kernel<<<NBLK, NTHR, 0, stream>>>(
            x, labels, lmask, bpe, W, bias, part_sum, part_cnt);
    }
    finalize_kernel<<<1, 64, 0, stream>>>(part_sum, part_cnt, (float*)d_out);
}

// Round 7
// 27.265 us; speedup vs baseline: 5.4756x; 5.4756x over previous
//
#include <hip/hip_runtime.h>
#include <hip/hip_bf16.h>

// Problem-fixed shapes (XLMRForTokenClassification: B=128, S=512, H=1024, L=9)
#define B_ 128
#define S_ 512
#define H_ 1024
#define L_ 9

#define NBLK 256        // 2 blocks per batch
#define NTHR 512        // 8 waves per block
#define WPB  8
#define SLOTS 3         // per-wave LDS row ring depth

// DPP-based wave64 sum: total lands in lane 63.
#define DPP_ADD_(v, ctrl, rm, bm)                                              \
    v += __int_as_float(__builtin_amdgcn_update_dpp(                           \
        0, __float_as_int(v), ctrl, rm, bm, true))

__device__ __forceinline__ float wave_sum63(float v) {
    DPP_ADD_(v, 0x111, 0xf, 0xf);  // row_shr:1
    DPP_ADD_(v, 0x112, 0xf, 0xf);  // row_shr:2
    DPP_ADD_(v, 0x114, 0xf, 0xe);  // row_shr:4
    DPP_ADD_(v, 0x118, 0xf, 0xc);  // row_shr:8
    DPP_ADD_(v, 0x142, 0xa, 0xf);  // row_bcast:15 -> rows 1,3
    DPP_ADD_(v, 0x143, 0xc, 0xf);  // row_bcast:31 -> rows 2,3
    return v;
}

// ---------------------------------------------------------------------------
// Fused compute kernel. blockIdx -> (batch = blk>>1, half = blk&1).
// Phase A: ballot scans -> per-batch item list in LDS; bias-only NLL + count.
// Phase B: per-wave PRIVATE 3-slot LDS row ring filled by global_load_lds
//   (width 16, wave-uniform LDS base) -> zero row-buffer VGPRs. Manual
//   counted s_waitcnt vmcnt(8/4/0): slots are per-wave, no barriers. Rows
//   consumed via conflict-free ds_read_b128. W stays in registers (144 VGPR);
//   one vmcnt(0) drains W + int loads before the pipeline so gll counting is
//   exact. DPP reduction for the 9 dots; softmax on lane 63.
// ---------------------------------------------------------------------------
__global__ __launch_bounds__(NTHR, 2) void fused_kernel(
    const float* __restrict__ x,       // [B,S,H]
    const int*   __restrict__ labels,  // [B,S]
    const int*   __restrict__ lmask,   // [B,S]
    const int*   __restrict__ bpe,     // [B,S]
    const float* __restrict__ W,       // [L,H]
    const float* __restrict__ bias,    // [L]
    float* __restrict__ part_sum,      // [NBLK]
    float* __restrict__ part_cnt)      // [NBLK]
{
    const int tid  = threadIdx.x;
    const int lane = tid & 63;
    const int wv   = tid >> 6;
    const int b    = blockIdx.x >> 1;
    const int half = blockIdx.x & 1;

    __shared__ float    ring[WPB][SLOTS][H_];   // 96 KB, per-wave private
    __shared__ int      wcnt[WPB], wcnt2[WPB];
    __shared__ int      srcbuf[S_];
    __shared__ unsigned items[S_];
    __shared__ float    red[WPB], redc[WPB];

    // ---- scan-critical int loads first ----
    const int gpos = b * S_ + tid;
    const int bpev = bpe[gpos];
    const int lab  = labels[gpos];
    const int lmv  = lmask[gpos];

    // ---- stage W into registers (latency hides under phase A) ----
    const float4* W4 = reinterpret_cast<const float4*>(W);
    float4 wreg[L_][4];
#pragma unroll
    for (int l = 0; l < L_; ++l)
#pragma unroll
        for (int k = 0; k < 4; ++k)
            wreg[l][k] = W4[l * (H_ / 4) + lane + 64 * k];
    float bl[L_];
#pragma unroll
    for (int l = 0; l < L_; ++l) bl[l] = bias[l];

    // ---- phase A: per-batch scans ----
    const unsigned long long lmlt = (1ull << lane) - 1ull;

    const int vv = (bpev == 1) ? 1 : 0;
    const unsigned long long ball = __ballot(vv != 0);
    const int rank = (int)__popcll(ball & lmlt);
    if (lane == 0) wcnt[wv] = (int)__popcll(ball);
    __syncthreads();
    int prefix = 0, n_valid = 0;
#pragma unroll
    for (int w = 0; w < WPB; ++w) {
        const int c = wcnt[w];
        if (w < wv) prefix += c;
        n_valid += c;
    }
    if (vv) srcbuf[prefix + rank] = tid;
    __syncthreads();

    const bool act = (lmv == 1) && (lab != 0);
    const bool rowitem = act && (tid < n_valid);
    const unsigned long long ball2 = __ballot(rowitem);
    const int rank2 = (int)__popcll(ball2 & lmlt);
    if (lane == 0) wcnt2[wv] = (int)__popcll(ball2);
    __syncthreads();
    int prefix2 = 0, m = 0;
#pragma unroll
    for (int w = 0; w < WPB; ++w) {
        const int c = wcnt2[w];
        if (w < wv) prefix2 += c;
        m += c;
    }
    if (rowitem)
        items[prefix2 + rank2] = ((unsigned)srcbuf[tid] << 4) | (unsigned)lab;

    // bias-only NLL (zeroed rows: logits == bias) + denominator (half==0 only)
    float bnll = 0.f, bc = 0.f;
    if (half == 0) {
        if (act && tid >= n_valid) {
            float mx = bl[0];
#pragma unroll
            for (int l = 1; l < L_; ++l) mx = fmaxf(mx, bl[l]);
            float se = 0.f;
#pragma unroll
            for (int l = 0; l < L_; ++l) se += __expf(bl[l] - mx);
            bnll = mx + __logf(se) - bl[lab];
        }
        bc = act ? 1.f : 0.f;
    }
    __syncthreads();   // items[] visible

    // ---- phase B ----
    const float* xb = x + (size_t)b * S_ * H_;
    const int p  = half + 2 * wv;                       // first item index
    const int nt = (m > p) ? ((m - p + 15) >> 4) : 0;   // my item count

    const int midx = p + 16 * lane;
    unsigned ereg = (midx < m) ? items[midx] : 0u;      // lane t: item p+16t

    float lsum = 0.f;

    // issue one row (4 KB) into my private slot via global_load_lds x4
    auto issue_row = [&](int slot, int t) {
        const unsigned e = (unsigned)__builtin_amdgcn_readlane((int)ereg, t);
        const float* g = xb + (size_t)(e >> 4) * H_ + (lane << 2);
        float* l = &ring[wv][slot][0];
#pragma unroll
        for (int k = 0; k < 4; ++k) {
            __builtin_amdgcn_global_load_lds(
                (const __attribute__((address_space(1))) void*)(g + k * 256),
                (__attribute__((address_space(3))) void*)(l + k * 256),
                16, 0, 0);
        }
    };

    auto compute_from = [&](int slot, int t) {
        const float4* sp = reinterpret_cast<const float4*>(&ring[wv][slot][0]);
        const float4 v0 = sp[lane];
        const float4 v1 = sp[lane + 64];
        const float4 v2 = sp[lane + 128];
        const float4 v3 = sp[lane + 192];
        float acc[L_];
#pragma unroll
        for (int l = 0; l < L_; ++l) {
            acc[l] = v0.x * wreg[l][0].x + v0.y * wreg[l][0].y
                   + v0.z * wreg[l][0].z + v0.w * wreg[l][0].w
                   + v1.x * wreg[l][1].x + v1.y * wreg[l][1].y
                   + v1.z * wreg[l][1].z + v1.w * wreg[l][1].w
                   + v2.x * wreg[l][2].x + v2.y * wreg[l][2].y
                   + v2.z * wreg[l][2].z + v2.w * wreg[l][2].w
                   + v3.x * wreg[l][3].x + v3.y * wreg[l][3].y
                   + v3.z * wreg[l][3].z + v3.w * wreg[l][3].w;
        }
#pragma unroll
        for (int l = 0; l < L_; ++l) acc[l] = wave_sum63(acc[l]);
        if (lane == 63) {
            const int lb = (int)(__builtin_amdgcn_readlane((int)ereg, t) & 0xF);
            float lg[L_];
#pragma unroll
            for (int l = 0; l < L_; ++l) lg[l] = acc[l] + bl[l];
            float mx = lg[0];
#pragma unroll
            for (int l = 1; l < L_; ++l) mx = fmaxf(mx, lg[l]);
            float se = 0.f;
#pragma unroll
            for (int l = 0; l < L_; ++l) se += __expf(lg[l] - mx);
            float sel = lg[0];
#pragma unroll
            for (int l = 1; l < L_; ++l) sel = (lb == l) ? lg[l] : sel;
            lsum += mx + __logf(se) - sel;
        }
    };

    // Drain W + int loads so gll vmcnt accounting below is exact.
    asm volatile("s_waitcnt vmcnt(0)" ::: "memory");

    if (nt > 0) {
        issue_row(0, 0);
        if (nt > 1) issue_row(1, 1);
        for (int t = 0; t < nt; ++t) {
            if (t + 2 < nt) issue_row((t + 2) % SLOTS, t + 2);
            // younger gll ops outstanding after this point:
            if (t + 2 < nt) {
                asm volatile("s_waitcnt vmcnt(8)" ::: "memory");
            } else if (t + 1 < nt) {
                asm volatile("s_waitcnt vmcnt(4)" ::: "memory");
            } else {
                asm volatile("s_waitcnt vmcnt(0)" ::: "memory");
            }
            __builtin_amdgcn_sched_barrier(0);
            compute_from(t % SLOTS, t);
        }
    }

    // ---- block reduce -> partial stores (finalize is a later dispatch) ----
    const float bs = wave_sum63(bnll);
    const float cs = wave_sum63(bc);
    if (lane == 63) { red[wv] = lsum + bs; redc[wv] = cs; }
    __syncthreads();
    if (tid == 0) {
        float a = 0.f, c = 0.f;
#pragma unroll
        for (int w = 0; w < WPB; ++w) { a += red[w]; c += redc[w]; }
        part_sum[blockIdx.x] = a;
        part_cnt[blockIdx.x] = c;
    }
}

// ---------------------------------------------------------------------------
// Finalize: reduce partials -> scalar loss
// ---------------------------------------------------------------------------
__global__ void finalize_kernel(const float* __restrict__ part_sum,
                                const float* __restrict__ part_cnt,
                                float* __restrict__ out) {
    const int lane = threadIdx.x;  // 64 threads
    float s = 0.f, c = 0.f;
    for (int i = lane; i < NBLK; i += 64) {
        s += part_sum[i];
        c += part_cnt[i];
    }
#pragma unroll
    for (int off = 32; off > 0; off >>= 1) {
        s += __shfl_xor(s, off, 64);
        c += __shfl_xor(c, off, 64);
    }
    if (lane == 0) out[0] = s / fmaxf(c, 1.0f);
}

extern "C" void kernel_launch(void* const* d_in, const int* in_sizes, int n_in,
                              void* d_out, int out_size, void* d_ws, size_t ws_size,
                              hipStream_t stream) {
    const float* x      = (const float*)d_in[0];  // [B,S,H] f32
    const int*   labels = (const int*)d_in[1];    // [B,S]
    const int*   lmask  = (const int*)d_in[2];    // [B,S]
    const int*   bpe    = (const int*)d_in[3];    // [B,S]
    const float* W      = (const float*)d_in[4];  // [L,H] f32
    const float* bias   = (const float*)d_in[5];  // [L]  f32

    // Workspace: part_sum[NBLK] | part_cnt[NBLK]
    float* part_sum = (float*)d_ws;
    float* part_cnt = part_sum + NBLK;

    fused_kernel<<<NBLK, NTHR, 0, stream>>>(
        x, labels, lmask, bpe, W, bias, part_sum, part_cnt);
    finalize_kernel<<<1, 64, 0, stream>>>(part_sum, part_cnt, (float*)d_out);
}